// Round 4
// baseline (812.838 us; speedup 1.0000x reference)
//
#include <hip/hip_runtime.h>

typedef unsigned short u16;
typedef __bf16 bf16x8 __attribute__((ext_vector_type(8)));
typedef short  s16x8  __attribute__((ext_vector_type(8)));
typedef float  f32x4  __attribute__((ext_vector_type(4)));

// --- builtin operand-type hedge: pick whichever vector type the bf16 MFMA
// builtin accepts on this toolchain.
template <bool B, class T, class F> struct cond_t { using type = T; };
template <class T, class F> struct cond_t<false, T, F> { using type = F; };
template <typename T>
__device__ auto probe_mfma(int)
    -> decltype(__builtin_amdgcn_mfma_f32_16x16x32_bf16(T{}, T{}, f32x4{}, 0, 0, 0), (char)0);
template <typename T> __device__ short probe_mfma(...);
using frag_t = typename cond_t<sizeof(probe_mfma<bf16x8>(0)) == 1, bf16x8, s16x8>::type;
#define MFMA(a, b, c) __builtin_amdgcn_mfma_f32_16x16x32_bf16((a), (b), (c), 0, 0, 0)

__device__ __forceinline__ float bf2f(u16 u) {
  unsigned int x = ((unsigned int)u) << 16; float f; __builtin_memcpy(&f, &x, 4); return f;
}
__device__ __forceinline__ u16 f2bf(float f) {
  unsigned int x; __builtin_memcpy(&x, &f, 4);
  x += 0x7fffu + ((x >> 16) & 1u);  // RNE
  return (u16)(x >> 16);
}
__device__ __forceinline__ float fast_rcp(float x) { return __builtin_amdgcn_rcpf(x); }
__device__ __forceinline__ float tanh_fast(float x) {
  float t = __expf(2.0f * x);
  return 1.0f - 2.0f * fast_rcp(1.0f + t);
}
__device__ __forceinline__ float gelu_f(float x) {
  float x3 = x * x * x;
  return 0.5f * x * (1.0f + tanh_fast(0.7978845608028654f * x + 0.035677408136300125f * x3));
}
__device__ __forceinline__ float sigmoid_fast(float x) {
  return fast_rcp(1.0f + __expf(-x));
}

// async global->LDS, 16B per lane; LDS dest is wave-uniform base + lane*16
typedef const __attribute__((address_space(1))) void gvoid_t;
typedef __attribute__((address_space(3))) void lvoid_t;
__device__ __forceinline__ void gl16(const u16* g, char* l) {
  __builtin_amdgcn_global_load_lds((gvoid_t*)g, (lvoid_t*)l, 16, 0, 0);
}

// ---------- weight transpose+cast: dst[b][n][k] (bf16) = src[b][k][n] (f32) ----------
__global__ __launch_bounds__(256) void k_tr(const float* __restrict__ src, u16* __restrict__ dst,
                                            int batch, int K, int N) {
  long KN = (long)K * N;
  long total = (long)batch * KN;
  for (long i = (long)blockIdx.x * blockDim.x + threadIdx.x; i < total;
       i += (long)gridDim.x * blockDim.x) {
    long b = i / KN; long rem = i - b * KN;
    long n = rem / K; long k = rem - n * K;
    dst[i] = f2bf(src[b * KN + k * N + n]);
  }
}

// ---------- K1: LayerNorm(x) -> xn (bf16, ws) ; sigmoid gates -> f32 (ws) ----------
__global__ __launch_bounds__(256) void k1_ln_gate(
    const float* __restrict__ x, const float* __restrict__ ng, const float* __restrict__ nb,
    const float* __restrict__ gW, const float* __restrict__ gb,
    u16* __restrict__ xn, float* __restrict__ gate) {
  const int lane = threadIdx.x & 63;
  const long t = (long)blockIdx.x * 4 + (threadIdx.x >> 6);
  float4 a0 = *(const float4*)(x + t * 512 + lane * 8);
  float4 a1 = *(const float4*)(x + t * 512 + lane * 8 + 4);
  float f[8] = {a0.x, a0.y, a0.z, a0.w, a1.x, a1.y, a1.z, a1.w};
  float s = 0.f, ss = 0.f;
#pragma unroll
  for (int j = 0; j < 8; j++) { s += f[j]; ss += f[j] * f[j]; }
#pragma unroll
  for (int m = 1; m < 64; m <<= 1) { s += __shfl_xor(s, m); ss += __shfl_xor(ss, m); }
  const float mean = s * (1.0f / 512.0f);
  const float rstd = rsqrtf(ss * (1.0f / 512.0f) - mean * mean + 1e-5f);
  float xf[8];
  union { uint4 q; u16 u[8]; } st;
#pragma unroll
  for (int j = 0; j < 8; j++) {
    xf[j] = (f[j] - mean) * rstd * ng[lane * 8 + j] + nb[lane * 8 + j];
    st.u[j] = f2bf(xf[j]);
  }
  *(uint4*)(xn + t * 512 + lane * 8) = st.q;
  for (int h = 0; h < 4; h++) {
    float p = 0.f;
#pragma unroll
    for (int j = 0; j < 8; j++) p += xf[j] * gW[h * 512 + lane * 8 + j];
#pragma unroll
    for (int m = 1; m < 64; m <<= 1) p += __shfl_xor(p, m);
    if (lane == 0) gate[t * 4 + h] = sigmoid_fast(p + gb[h]);
  }
}

// ---------- K2: per (128-token tile, head) fused head pipeline (v5, BM=128) ----------
// 512 threads = 8 waves. Phase1: 2x(4 row-grp)x(2 col-grp) wave split, double-
// buffered gl16 staging (A 8KB + B 16KB per buf, pair-swizzled source).
// LDS plan (peak 71712 B -> 2 blocks/CU, 16 waves/CU):
//   phase1: sA0@0 8KB  sA1@8192   sB0@16384 16KB  sB1@32768 16KB
//   epi1 : sH @0 [128][512B] (XOR swz)   sLN @65536 (2KB)
//          sAB @67584 [16][256B]         sA2 @71680 (32B)
//   epi2 : sSt @0 [128][256B] (XOR swz)  sPA @32768 [128][64B]
//          attrB2 @40960 [128][64B]
//   out  : bounce over sSt rows (wave-local)
__global__ __launch_bounds__(512, 4) void k2_head(
    const u16* __restrict__ xn, const u16* __restrict__ hW1t, const float* __restrict__ hb1,
    const float* __restrict__ hlng, const float* __restrict__ hlnb,
    const u16* __restrict__ hW2t, const float* __restrict__ hb2,
    const float* __restrict__ attr, const u16* __restrict__ dynT,
    const float* __restrict__ gate, u16* __restrict__ outC) {
  __shared__ __align__(16) char smem[71712];
  const int tid = threadIdx.x;
  const int lane = tid & 63, wv = tid >> 6, q = lane >> 4, l15 = lane & 15;
  const int wq = wv >> 1, wc = wv & 1;
  // bijective XCD-chunked swizzle: 2048 blocks, 8 XCDs, 256 per chunk.
  // heads of the same token tile adjacent -> same XCD, xn tile L2-reused 4x.
  const int sw = ((blockIdx.x & 7) << 8) + (blockIdx.x >> 3);
  const int h = sw & 3;
  const long t0 = (long)(sw >> 2) * 128;
  const f32x4 vz = {0.f, 0.f, 0.f, 0.f};

  // ---------------- phase1: H' = xn[128x512] @ W1^T ------------------------------
  // staging source mapping (pair-swizzle, involution):
  //   LDS byte(row,c16) = (row>>1)*128 + ((((row&1)<<2)|c16) ^ ((row>>1)&7))*16
  const int pr = lane >> 3, posp = lane & 7;
  const int pos = posp ^ pr;
  const int rl = pr * 2 + (pos >> 2), ck = pos & 3;
  const u16* gA = xn + ((size_t)(t0 + wv * 16 + rl) << 9) + ck * 8;
  const u16* gB = hW1t + ((((size_t)h * 256) + wv * 16 + rl) << 9) + ck * 8;

  int afo[2], bfo[8];
#pragma unroll
  for (int i = 0; i < 2; i++) {
    int row = wq * 32 + i * 16 + l15;
    afo[i] = (row >> 1) * 128 + (((((row & 1) << 2) | q) ^ ((row >> 1) & 7)) << 4);
  }
#pragma unroll
  for (int nt = 0; nt < 8; nt++) {
    int row = wc * 128 + nt * 16 + l15;
    bfo[nt] = (row >> 1) * 128 + (((((row & 1) << 2) | q) ^ ((row >> 1) & 7)) << 4);
  }

  f32x4 acc[2][8];
#pragma unroll
  for (int i = 0; i < 2; i++)
#pragma unroll
    for (int nt = 0; nt < 8; nt++) acc[i][nt] = vz;

#define STAGE1(buf)                                                  \
  {                                                                  \
    gl16(gA, smem + (buf) * 8192 + wv * 1024);                       \
    gl16(gB, smem + 16384 + (buf) * 16384 + wv * 1024);              \
    gl16(gB + 65536, smem + 16384 + (buf) * 16384 + 8192 + wv * 1024); \
    gA += 32; gB += 32;                                              \
  }

  STAGE1(0);
  __syncthreads();
#pragma unroll 2
  for (int k = 0; k < 16; ++k) {
    const int cur = k & 1;
    if (k < 15) STAGE1(cur ^ 1);
    const char* Ab = smem + cur * 8192;
    const char* Bb = smem + 16384 + cur * 16384;
    frag_t a0 = *(const frag_t*)(Ab + afo[0]);
    frag_t a1 = *(const frag_t*)(Ab + afo[1]);
#pragma unroll
    for (int nt = 0; nt < 8; nt++) {
      frag_t bf = *(const frag_t*)(Bb + bfo[nt]);
      acc[0][nt] = MFMA(a0, bf, acc[0][nt]);
      acc[1][nt] = MFMA(a1, bf, acc[1][nt]);
    }
    __syncthreads();
  }
#undef STAGE1

  // ---------------- epi1: bias + LN(256) + gelu -> sH (bf16, XOR swz) ------------
  float bb[8], cg[8], cbv[8];
#pragma unroll
  for (int nt = 0; nt < 8; nt++) {
    int c = h * 256 + wc * 128 + nt * 16 + l15;
    bb[nt] = hb1[c]; cg[nt] = hlng[c]; cbv[nt] = hlnb[c];
  }
  float* sLN = (float*)(smem + 65536);
#pragma unroll
  for (int i = 0; i < 2; i++)
#pragma unroll
    for (int r = 0; r < 4; r++) {
      float s = 0.f, ss = 0.f;
#pragma unroll
      for (int nt = 0; nt < 8; nt++) { float v = acc[i][nt][r] + bb[nt]; s += v; ss = fmaf(v, v, ss); }
#pragma unroll
      for (int m = 1; m < 16; m <<= 1) { s += __shfl_xor(s, m); ss += __shfl_xor(ss, m); }
      if (l15 == 0) {
        int row = wq * 32 + i * 16 + q * 4 + r;
        sLN[row * 4 + wc * 2] = s; sLN[row * 4 + wc * 2 + 1] = ss;
      }
    }
  // attractor ||a||^2 -> sA2 (wave 0 only)
  float* sA2 = (float*)(smem + 71680);
  if (wv == 0) {
    int a = lane >> 3, jj = lane & 7;
    float s = 0.f;
#pragma unroll
    for (int d2 = 0; d2 < 16; d2++) { float v = attr[h * 1024 + a * 128 + jj * 16 + d2]; s = fmaf(v, v, s); }
#pragma unroll
    for (int m = 1; m < 8; m <<= 1) s += __shfl_xor(s, m);
    if (jj == 0) sA2[a] = s;
  }
  // attr as B-frag [a=16(8 valid)][k=d 128] -> sAB @67584 (XOR swz)
#pragma unroll
  for (int j = 0; j < 4; j++) {
    int idx = tid * 4 + j, ar = idx >> 7, d = idx & 127;
    u16 v = (ar < 8) ? f2bf(attr[h * 1024 + ar * 128 + d]) : (u16)0;
    *(u16*)(smem + 67584 + ar * 256 + ((2 * d) ^ ((ar & 7) << 4))) = v;
  }
  __syncthreads();
#pragma unroll
  for (int i = 0; i < 2; i++)
#pragma unroll
    for (int r = 0; r < 4; r++) {
      int row = wq * 32 + i * 16 + q * 4 + r;
      float s = sLN[row * 4] + sLN[row * 4 + 2], ss = sLN[row * 4 + 1] + sLN[row * 4 + 3];
      float mean = s * (1.f / 256.f);
      float rstd = rsqrtf(ss * (1.f / 256.f) - mean * mean + 1e-5f);
      float mr = -mean * rstd;
#pragma unroll
      for (int nt = 0; nt < 8; nt++) {
        float v = fmaf(acc[i][nt][r] + bb[nt], rstd, mr);
        v = fmaf(v, cg[nt], cbv[nt]);
        int col = wc * 128 + nt * 16 + l15;
        *(u16*)(smem + row * 512 + ((2 * col) ^ ((row & 7) << 4))) = f2bf(gelu_f(v));
      }
    }
  __syncthreads();

  // ---------------- phase2: state = H @ W2^T ; B-frags direct from global --------
  f32x4 acc2[8];
#pragma unroll
  for (int nt = 0; nt < 8; nt++) acc2[nt] = vz;
  {
    const int rb2 = (wv * 16 + l15) * 512, sw2 = (l15 & 7) << 4;
    const u16* pB2[8];
#pragma unroll
    for (int nt = 0; nt < 8; nt++)
      pB2[nt] = hW2t + ((((size_t)h * 128) + nt * 16 + l15) << 8) + q * 8;
#pragma unroll
    for (int kb = 0; kb < 256; kb += 32) {
      frag_t af = *(const frag_t*)(smem + rb2 + ((kb * 2 + q * 16) ^ sw2));
#pragma unroll
      for (int nt = 0; nt < 8; nt++) {
        frag_t bf = *(const frag_t*)(pB2[nt] + kb);
        acc2[nt] = MFMA(af, bf, acc2[nt]);
      }
    }
  }
#pragma unroll
  for (int nt = 0; nt < 8; nt++) {
    float b2 = hb2[h * 128 + nt * 16 + l15];
#pragma unroll
    for (int r = 0; r < 4; r++) acc2[nt][r] += b2;
  }
  float s2v[4];
#pragma unroll
  for (int r = 0; r < 4; r++) {
    float s = 0.f;
#pragma unroll
    for (int nt = 0; nt < 8; nt++) s = fmaf(acc2[nt][r], acc2[nt][r], s);
#pragma unroll
    for (int m = 1; m < 16; m <<= 1) s += __shfl_xor(s, m);
    s2v[r] = s;
  }
  __syncthreads();  // sH dead

  // state -> sSt (bf16, XOR swz) @0 ; attrB2[n=col][k=a] -> @40960
#pragma unroll
  for (int nt = 0; nt < 8; nt++)
#pragma unroll
    for (int r = 0; r < 4; r++) {
      int row = wv * 16 + q * 4 + r, col = nt * 16 + l15;
      *(u16*)(smem + row * 256 + ((2 * col) ^ ((row & 7) << 4))) = f2bf(acc2[nt][r]);
    }
#pragma unroll
  for (int j = 0; j < 8; j++) {
    int idx = tid * 8 + j, row = idx >> 5, kk = idx & 31;
    u16 v = (kk < 8) ? f2bf(attr[h * 1024 + kk * 128 + row]) : (u16)0;
    *(u16*)(smem + 40960 + row * 64 + ((2 * kk) ^ ((row & 3) << 4))) = v;
  }
  __syncthreads();

  // ---------------- phase3: dyn = state @ dynT ; sa = state @ attr^T (fused) -----
  f32x4 dacc[8], sacc = vz;
#pragma unroll
  for (int nt = 0; nt < 8; nt++) dacc[nt] = vz;
  {
    const int rb3 = (wv * 16 + l15) * 256, sw3 = (l15 & 7) << 4;
    const u16* pD[8];
#pragma unroll
    for (int nt = 0; nt < 8; nt++)
      pD[nt] = dynT + ((((size_t)h * 128) + nt * 16 + l15) << 7) + q * 8;
#pragma unroll
    for (int kb = 0; kb < 128; kb += 32) {
      const int ko = (kb * 2 + q * 16) ^ sw3;
      frag_t af = *(const frag_t*)(smem + rb3 + ko);
      frag_t ab = *(const frag_t*)(smem + 67584 + l15 * 256 + ko);
      sacc = MFMA(af, ab, sacc);
#pragma unroll
      for (int nt = 0; nt < 8; nt++) {
        frag_t bf = *(const frag_t*)(pD[nt] + kb);
        dacc[nt] = MFMA(af, bf, dacc[nt]);
      }
    }
  }

  // ---------------- softmax over 8 attractors (lane-parallel) --------------------
  const float dscale = 0.088388347648318447f;  // 1/sqrt(128)
  float g01[4];
#pragma unroll
  for (int r = 0; r < 4; r++)
    g01[r] = gate[(t0 + wv * 16 + q * 4 + r) * 4 + h] * 0.1f;
  const float a2l = (l15 < 8) ? ((const float*)(smem + 71680))[l15] : 0.f;
#pragma unroll
  for (int r = 0; r < 4; r++) {
    float lg = -3.0e38f;
    if (l15 < 8) {
      float d2 = fmaxf(fmaf(-2.f, sacc[r], s2v[r] + a2l), 0.f);
      lg = -sqrtf(d2) * dscale;
    }
    float mx = lg;
#pragma unroll
    for (int m = 1; m < 16; m <<= 1) mx = fmaxf(mx, __shfl_xor(mx, m));
    float p = __expf(lg - mx), den = p;
#pragma unroll
    for (int m = 1; m < 16; m <<= 1) den += __shfl_xor(den, m);
    p *= fast_rcp(den);
    int row = wv * 16 + q * 4 + r;
    *(u16*)(smem + 32768 + row * 64 + ((2 * l15) ^ ((row & 3) << 4))) = f2bf(p);
  }

  // pre-combine (frees acc2): pre = state + g*(tanh(dyn) - state)
#pragma unroll
  for (int nt = 0; nt < 8; nt++)
#pragma unroll
    for (int r = 0; r < 4; r++)
      dacc[nt][r] = acc2[nt][r] + g01[r] * (tanh_fast(dacc[nt][r]) - acc2[nt][r]);

  // ---------------- attr_infl = P @ attr  (one K=32 MFMA per col-tile) -----------
  f32x4 aacc[8];
#pragma unroll
  for (int nt = 0; nt < 8; nt++) aacc[nt] = vz;
  {
    const int rowa = wv * 16 + l15;
    frag_t ap = *(const frag_t*)(smem + 32768 + rowa * 64 + ((q * 16) ^ ((l15 & 3) << 4)));
#pragma unroll
    for (int nt = 0; nt < 8; nt++) {
      int rowb = nt * 16 + l15;
      frag_t bf = *(const frag_t*)(smem + 40960 + rowb * 64 + ((q * 16) ^ ((l15 & 3) << 4)));
      aacc[nt] = MFMA(ap, bf, aacc[nt]);
    }
  }

  // ---------------- head_out: wave-local LDS bounce -> 16B coalesced stores ------
  // rows [wv*16 .. wv*16+16) of smem@0 are only touched by this wave -> no barrier.
#pragma unroll
  for (int r = 0; r < 4; r++) {
    int row = wv * 16 + q * 4 + r;
    int key = (row >> 2) & 3;
#pragma unroll
    for (int nt = 0; nt < 8; nt++) {
      int col = nt * 16 + l15;
      float ho = dacc[nt][r] + g01[r] * aacc[nt][r];
      *(u16*)(smem + row * 256 + ((2 * col) ^ (key << 5))) = f2bf(ho);
    }
  }
  {
    const int row = tid >> 2;              // rows wv*16 .. wv*16+15 for this wave
    const int key = (row >> 2) & 3;
    const long t = t0 + row;
#pragma unroll
    for (int j = 0; j < 4; j++) {
      int c = (tid & 3) + 4 * j;
      uint4 v = *(const uint4*)(smem + row * 256 + ((c << 4) ^ (key << 5)));
      *(uint4*)(outC + t * 1024 + h * 128 + c * 8) = v;
    }
  }
}

// ---------- K3: o1 = gelu(LN(comb @ oW1 + ob1)) ; comb/o1 interleaved in d_out ----------
// 2-phase template: A-frags direct global; B double-buffered in LDS via
// global_load_lds (pair-swizzled), ONE barrier per K-step; col-split waves
// (each B-frag feeds 4 MFMAs).
__global__ __launch_bounds__(256, 2) void k3_mlp1(
    const u16* __restrict__ inp, const u16* __restrict__ oW1t,
    const float* __restrict__ ob1, const float* __restrict__ olng, const float* __restrict__ olnb,
    u16* __restrict__ outp) {
  __shared__ __align__(16) char smem[67584];  // 2 x 32KB B slabs + 2KB sLN
  const int tid = threadIdx.x, lane = tid & 63, wv = tid >> 6, q = lane >> 4, l15 = lane & 15;
  const long t0 = (long)blockIdx.x * 64;
  const f32x4 vz = {0.f, 0.f, 0.f, 0.f};
  f32x4 acc[4][8];
#pragma unroll
  for (int i = 0; i < 4; i++)
#pragma unroll
    for (int nt = 0; nt < 8; nt++) acc[i][nt] = vz;

  // staging source (pre-swizzled): LDS slab layout
  //   byte(row,c) = (row>>1)*128 + (((row&1)<<2 | c) ^ ((row>>1)&7))*16
  const int pr = lane >> 3, pos = (lane & 7) ^ pr;
  const int rl = pr * 2 + (pos >> 2), ck = pos & 3;
  const u16* gB = oW1t + ((size_t)(wv * 128 + rl) << 9) + ck * 8;
  // read offsets: this wave's cols = wv*128 + nt*16 + l15
  int bfo[8];
#pragma unroll
  for (int nt = 0; nt < 8; nt++) {
    int row = wv * 128 + nt * 16 + l15;
    bfo[nt] = (row >> 1) * 128 + (((((row & 1) << 2) | q) ^ ((row >> 1) & 7)) << 4);
  }
  const u16* pA = inp + (((size_t)(t0 + l15)) << 10) + q * 8;

#define STG3(buf, kb)                                                      \
  {                                                                        \
    char* l = smem + (buf) * 32768 + wv * 8192;                            \
    _Pragma("unroll") for (int m = 0; m < 8; m++)                          \
        gl16(gB + m * 8192 + (kb), l + m * 1024);                          \
  }

  STG3(0, 0);
  __syncthreads();
  for (int k = 0; k < 16; ++k) {
    const int kb = k * 32, cur = k & 1;
    frag_t a[4];
#pragma unroll
    for (int i = 0; i < 4; i++) a[i] = *(const frag_t*)(pA + i * 16384 + kb);
    if (k < 15) STG3(cur ^ 1, kb + 32);
    const char* Bb = smem + cur * 32768;
#pragma unroll
    for (int nt = 0; nt < 8; nt++) {
      frag_t bf = *(const frag_t*)(Bb + bfo[nt]);
#pragma unroll
      for (int i = 0; i < 4; i++) acc[i][nt] = MFMA(a[i], bf, acc[i][nt]);
    }
    __syncthreads();
  }
#undef STG3

  float bb[8], cg[8], cb2[8];
#pragma unroll
  for (int nt = 0; nt < 8; nt++) {
    int col = wv * 128 + nt * 16 + l15;
    bb[nt] = ob1[col]; cg[nt] = olng[col]; cb2[nt] = olnb[col];
  }
  float* sLN = (float*)(smem + 65536);
#pragma unroll
  for (int i = 0; i < 4; i++)
#pragma unroll
    for (int r = 0; r < 4; r++) {
      float s = 0.f, ss = 0.f;
#pragma unroll
      for (int nt = 0; nt < 8; nt++) { float v = acc[i][nt][r] + bb[nt]; s += v; ss = fmaf(v, v, ss); }
#pragma unroll
      for (int m = 1; m < 16; m <<= 1) { s += __shfl_xor(s, m); ss += __shfl_xor(ss, m); }
      if (l15 == 0) {
        int row = i * 16 + q * 4 + r;
        sLN[row * 8 + wv * 2] = s; sLN[row * 8 + wv * 2 + 1] = ss;
      }
    }
  __syncthreads();
#pragma unroll
  for (int i = 0; i < 4; i++)
#pragma unroll
    for (int r = 0; r < 4; r++) {
      int row = i * 16 + q * 4 + r;
      float4 p0 = *(const float4*)&sLN[row * 8];
      float4 p1 = *(const float4*)&sLN[row * 8 + 4];
      float s = p0.x + p0.z + p1.x + p1.z, ss = p0.y + p0.w + p1.y + p1.w;
      float mean = s * (1.f / 512.f);
      float rstd = rsqrtf(ss * (1.f / 512.f) - mean * mean + 1e-5f);
      const long t = t0 + row;
#pragma unroll
      for (int nt = 0; nt < 8; nt++) {
        int col = wv * 128 + nt * 16 + l15;
        float v = (acc[i][nt][r] + bb[nt] - mean) * rstd * cg[nt] + cb2[nt];
        outp[t * 1024 + col] = f2bf(gelu_f(v));
      }
    }
}

// ---------- K4: out = xn + o1 @ oW2 + ob2 ; o1 bf16 (interleaved), out f32 ----------
__global__ __launch_bounds__(256, 2) void k4_mlp2(
    const u16* __restrict__ inp, const u16* __restrict__ oW2t,
    const float* __restrict__ ob2, const u16* __restrict__ xn,
    float* __restrict__ outp) {
  __shared__ __align__(16) char smem[65536];  // 2 x 32KB B slabs
  const int tid = threadIdx.x, lane = tid & 63, wv = tid >> 6, q = lane >> 4, l15 = lane & 15;
  const long t0 = (long)blockIdx.x * 64;
  const f32x4 vz = {0.f, 0.f, 0.f, 0.f};
  f32x4 acc[4][8];
#pragma unroll
  for (int i = 0; i < 4; i++)
#pragma unroll
    for (int nt = 0; nt < 8; nt++) acc[i][nt] = vz;

  const int pr = lane >> 3, pos = (lane & 7) ^ pr;
  const int rl = pr * 2 + (pos >> 2), ck = pos & 3;
  const u16* gB = oW2t + ((size_t)(wv * 128 + rl) << 9) + ck * 8;
  int bfo[8];
#pragma unroll
  for (int nt = 0; nt < 8; nt++) {
    int row = wv * 128 + nt * 16 + l15;
    bfo[nt] = (row >> 1) * 128 + (((((row & 1) << 2) | q) ^ ((row >> 1) & 7)) << 4);
  }
  const u16* pA = inp + (((size_t)(t0 + l15)) << 10) + q * 8;

#define STG4(buf, kb)                                                      \
  {                                                                        \
    char* l = smem + (buf) * 32768 + wv * 8192;                            \
    _Pragma("unroll") for (int m = 0; m < 8; m++)                          \
        gl16(gB + m * 8192 + (kb), l + m * 1024);                          \
  }

  STG4(0, 0);
  __syncthreads();
  for (int k = 0; k < 16; ++k) {
    const int kb = k * 32, cur = k & 1;
    frag_t a[4];
#pragma unroll
    for (int i = 0; i < 4; i++) a[i] = *(const frag_t*)(pA + i * 16384 + kb);
    if (k < 15) STG4(cur ^ 1, kb + 32);
    const char* Bb = smem + cur * 32768;
#pragma unroll
    for (int nt = 0; nt < 8; nt++) {
      frag_t bf = *(const frag_t*)(Bb + bfo[nt]);
#pragma unroll
      for (int i = 0; i < 4; i++) acc[i][nt] = MFMA(a[i], bf, acc[i][nt]);
    }
    __syncthreads();
  }
#undef STG4

#pragma unroll
  for (int i = 0; i < 4; i++)
#pragma unroll
    for (int r = 0; r < 4; r++) {
      int row = i * 16 + q * 4 + r;
      const long t = t0 + row;
#pragma unroll
      for (int nt = 0; nt < 8; nt++) {
        int col = wv * 128 + nt * 16 + l15;
        float v = acc[i][nt][r] + ob2[col] + bf2f(xn[t * 512 + col]);
        outp[t * 512 + col] = v;
      }
    }
}

extern "C" void kernel_launch(void* const* d_in, const int* in_sizes, int n_in,
                              void* d_out, int out_size, void* d_ws, size_t ws_size,
                              hipStream_t stream) {
  const float* x    = (const float*)d_in[0];
  const float* ng   = (const float*)d_in[1];
  const float* nbp  = (const float*)d_in[2];
  const float* hW1  = (const float*)d_in[3];
  const float* hb1  = (const float*)d_in[4];
  const float* hlng = (const float*)d_in[5];
  const float* hlnb = (const float*)d_in[6];
  const float* hW2  = (const float*)d_in[7];
  const float* hb2  = (const float*)d_in[8];
  const float* attr = (const float*)d_in[9];
  const float* dyn  = (const float*)d_in[10];
  const float* gW   = (const float*)d_in[11];
  const float* gb   = (const float*)d_in[12];
  const float* oW1  = (const float*)d_in[13];
  const float* ob1  = (const float*)d_in[14];
  const float* olng = (const float*)d_in[15];
  const float* olnb = (const float*)d_in[16];
  const float* oW2  = (const float*)d_in[17];
  const float* ob2  = (const float*)d_in[18];

  char* ws = (char*)d_ws;
  u16*   xn   = (u16*)ws;                   // 67,108,864 B  [65536,512] bf16
  float* gate = (float*)(ws + 67108864);    //  1,048,576 B  [65536,4] f32
  u16*   wT   = (u16*)(ws + 68157440);      //  2,490,368 B  transposed bf16 weights
  u16* hW1t = wT;                // [4][256][512]
  u16* hW2t = wT + 524288;       // [4][128][256]
  u16* dynT = wT + 655360;       // [4][128][128]
  u16* oW1t = wT + 720896;       // [512][512]
  u16* oW2t = wT + 983040;       // [512][512]

  k_tr<<<512, 256, 0, stream>>>(hW1, hW1t, 4, 512, 256);
  k_tr<<<128, 256, 0, stream>>>(hW2, hW2t, 4, 256, 128);
  k_tr<<<64, 256, 0, stream>>>(dyn, dynT, 4, 128, 128);
  k_tr<<<256, 256, 0, stream>>>(oW1, oW1t, 1, 512, 512);
  k_tr<<<256, 256, 0, stream>>>(oW2, oW2t, 1, 512, 512);

  k1_ln_gate<<<16384, 256, 0, stream>>>(x, ng, nbp, gW, gb, xn, gate);

  // d_out doubles as bf16 scratch, per-row interleaved:
  //   row t: u16 [t*1024 .. t*1024+512) = comb, [t*1024+512 .. t*1024+1024) = o1
  u16* cb = (u16*)d_out;
  k2_head<<<2048, 512, 0, stream>>>(xn, hW1t, hb1, hlng, hlnb, hW2t, hb2,
                                    attr, dynT, gate, cb);
  k3_mlp1<<<1024, 256, 0, stream>>>(cb, oW1t, ob1, olng, olnb, cb + 512);
  k4_mlp2<<<1024, 256, 0, stream>>>(cb + 512, oW2t, ob2, xn, (float*)d_out);
}

// Round 7
// 734.143 us; speedup vs baseline: 1.1072x; 1.1072x over previous
//
#include <hip/hip_runtime.h>

typedef unsigned short u16;
typedef __bf16 bf16x8 __attribute__((ext_vector_type(8)));
typedef short  s16x8  __attribute__((ext_vector_type(8)));
typedef float  f32x4  __attribute__((ext_vector_type(4)));

// --- builtin operand-type hedge ---
template <bool B, class T, class F> struct cond_t { using type = T; };
template <class T, class F> struct cond_t<false, T, F> { using type = F; };
template <typename T>
__device__ auto probe_mfma(int)
    -> decltype(__builtin_amdgcn_mfma_f32_16x16x32_bf16(T{}, T{}, f32x4{}, 0, 0, 0), (char)0);
template <typename T> __device__ short probe_mfma(...);
using frag_t = typename cond_t<sizeof(probe_mfma<bf16x8>(0)) == 1, bf16x8, s16x8>::type;
#define MFMA(a, b, c) __builtin_amdgcn_mfma_f32_16x16x32_bf16((a), (b), (c), 0, 0, 0)

__device__ __forceinline__ float bf2f(u16 u) {
  unsigned int x = ((unsigned int)u) << 16; float f; __builtin_memcpy(&f, &x, 4); return f;
}
__device__ __forceinline__ u16 f2bf(float f) {
  unsigned int x; __builtin_memcpy(&x, &f, 4);
  x += 0x7fffu + ((x >> 16) & 1u);  // RNE
  return (u16)(x >> 16);
}
__device__ __forceinline__ float fast_rcp(float x) { return __builtin_amdgcn_rcpf(x); }
__device__ __forceinline__ float tanh_fast(float x) {
  float t = __expf(2.0f * x);
  return 1.0f - 2.0f * fast_rcp(1.0f + t);
}
__device__ __forceinline__ float gelu_f(float x) {
  float x3 = x * x * x;
  return 0.5f * x * (1.0f + tanh_fast(0.7978845608028654f * x + 0.035677408136300125f * x3));
}
__device__ __forceinline__ float sigmoid_fast(float x) {
  return fast_rcp(1.0f + __expf(-x));
}

// async global->LDS, 16B per lane; LDS dest is wave-uniform base + lane*16
typedef const __attribute__((address_space(1))) void gvoid_t;
typedef __attribute__((address_space(3))) void lvoid_t;
__device__ __forceinline__ void gl16(const u16* g, char* l) {
  __builtin_amdgcn_global_load_lds((gvoid_t*)g, (lvoid_t*)l, 16, 0, 0);
}

// ---------- merged weight transpose+cast (single launch, 5 segments) ----------
// dst[b][n][k] (bf16) = src[b][k][n] (f32); dst offsets match ws layout.
__global__ __launch_bounds__(256) void k_tr5(
    const float* __restrict__ hW1, const float* __restrict__ hW2,
    const float* __restrict__ dyn, const float* __restrict__ oW1,
    const float* __restrict__ oW2, u16* __restrict__ wT) {
  long i = (long)blockIdx.x * 256 + threadIdx.x;
  const long stride = (long)gridDim.x * 256;
  for (; i < 1245184; i += stride) {
    const float* src; long rem; int K, N; long dof;
    if (i < 524288)      { src = hW1; rem = i;          K = 512; N = 256; dof = 0; }
    else if (i < 655360) { src = hW2; rem = i - 524288; K = 256; N = 128; dof = 524288; }
    else if (i < 720896) { src = dyn; rem = i - 655360; K = 128; N = 128; dof = 655360; }
    else if (i < 983040) { src = oW1; rem = i - 720896; K = 512; N = 512; dof = 720896; }
    else                 { src = oW2; rem = i - 983040; K = 512; N = 512; dof = 983040; }
    long KN = (long)K * N;
    long b = rem / KN; long r2 = rem - b * KN;
    long n = r2 / K;  long k = r2 - n * K;
    wT[dof + rem] = f2bf(src[b * KN + k * N + n]);
  }
}

// ---------- K1: LayerNorm(x) -> xn (bf16, ws) ; sigmoid gates -> f32 (ws) ----------
__global__ __launch_bounds__(256) void k1_ln_gate(
    const float* __restrict__ x, const float* __restrict__ ng, const float* __restrict__ nb,
    const float* __restrict__ gW, const float* __restrict__ gb,
    u16* __restrict__ xn, float* __restrict__ gate) {
  const int lane = threadIdx.x & 63;
  const long t = (long)blockIdx.x * 4 + (threadIdx.x >> 6);
  float4 a0 = *(const float4*)(x + t * 512 + lane * 8);
  float4 a1 = *(const float4*)(x + t * 512 + lane * 8 + 4);
  float f[8] = {a0.x, a0.y, a0.z, a0.w, a1.x, a1.y, a1.z, a1.w};
  float s = 0.f, ss = 0.f;
#pragma unroll
  for (int j = 0; j < 8; j++) { s += f[j]; ss += f[j] * f[j]; }
#pragma unroll
  for (int m = 1; m < 64; m <<= 1) { s += __shfl_xor(s, m); ss += __shfl_xor(ss, m); }
  const float mean = s * (1.0f / 512.0f);
  const float rstd = rsqrtf(ss * (1.0f / 512.0f) - mean * mean + 1e-5f);
  float xf[8];
  union { uint4 q; u16 u[8]; } st;
#pragma unroll
  for (int j = 0; j < 8; j++) {
    xf[j] = (f[j] - mean) * rstd * ng[lane * 8 + j] + nb[lane * 8 + j];
    st.u[j] = f2bf(xf[j]);
  }
  *(uint4*)(xn + t * 512 + lane * 8) = st.q;
  for (int h = 0; h < 4; h++) {
    float p = 0.f;
#pragma unroll
    for (int j = 0; j < 8; j++) p += xf[j] * gW[h * 512 + lane * 8 + j];
#pragma unroll
    for (int m = 1; m < 64; m <<= 1) p += __shfl_xor(p, m);
    if (lane == 0) gate[t * 4 + h] = sigmoid_fast(p + gb[h]);
  }
}

// ---------- K2: per (64-token tile, head) fused head pipeline (round-3 v4, verified) ----------
// = round-1 structure (double-buffered gl16 phase 1) + flat-grid XCD-chunked
// swizzle + coalesced 16B bounce-store epilogue.
// LDS plan (peak exactly 40960 B -> 4 blocks/CU):
//   phase1: sA0@0 4KB  sA1@4096 4KB   sB0@8192 16KB  sB1@24576 16KB
//   epi1:  sH @0 [64][512B] (XOR swz)      sLN @32768 (1KB)
//          sAB @33792 [16][256B] (attr as B-frag)   sA2 @37888 (64B)
//   epi2:  sSt @0 [64][256B] (XOR swz)     sPA @16384 [64][64B]
//          attrB2 @20480 [128][64B]
//   out  : bounce @0 [64][256B] (wave-local, key=(row>>2)&3 swizzle)
__global__ __launch_bounds__(256, 4) void k2_head(
    const u16* __restrict__ xn, const u16* __restrict__ hW1t, const float* __restrict__ hb1,
    const float* __restrict__ hlng, const float* __restrict__ hlnb,
    const u16* __restrict__ hW2t, const float* __restrict__ hb2,
    const float* __restrict__ attr, const u16* __restrict__ dynT,
    const float* __restrict__ gate, u16* __restrict__ outC) {
  __shared__ __align__(16) char smem[40960];
  const int tid = threadIdx.x;
  const int lane = tid & 63, wv = tid >> 6, q = lane >> 4, l15 = lane & 15;
  const int wr = wv >> 1, wc = wv & 1;
  // bijective XCD-chunked swizzle: 4096 blocks, 8 XCDs, 512 per chunk.
  const int sw = ((blockIdx.x & 7) << 9) + (blockIdx.x >> 3);
  const int h = sw & 3;
  const long t0 = (long)(sw >> 2) * 64;
  const f32x4 vz = {0.f, 0.f, 0.f, 0.f};

  // ---------------- phase1: H' = xn[64x512] @ W1^T  (2x2 wave split) -------------
  const int pr = lane >> 3, posp = lane & 7;
  const int pos = posp ^ pr;           // involution
  const int rl = pr * 2 + (pos >> 2), ck = pos & 3;
  const u16* gA = xn + ((size_t)(t0 + wv * 16 + rl) << 9) + ck * 8;
  const u16* gB = hW1t + ((((size_t)h * 256) + wv * 64 + rl) << 9) + ck * 8;
  char* const lA = smem + wv * 1024;
  char* const lB = smem + 8192 + wv * 4096;

  int afo[2], bfo[8];
#pragma unroll
  for (int i = 0; i < 2; i++) {
    int row = wr * 32 + i * 16 + l15;
    afo[i] = (row >> 1) * 128 + (((((row & 1) << 2) | q) ^ ((row >> 1) & 7)) << 4);
  }
#pragma unroll
  for (int nt = 0; nt < 8; nt++) {
    int row = wc * 128 + nt * 16 + l15;
    bfo[nt] = (row >> 1) * 128 + (((((row & 1) << 2) | q) ^ ((row >> 1) & 7)) << 4);
  }

  f32x4 acc[2][8];
#pragma unroll
  for (int i = 0; i < 2; i++)
#pragma unroll
    for (int nt = 0; nt < 8; nt++) acc[i][nt] = vz;

#define STAGE1(buf)                                     \
  {                                                     \
    gl16(gA, lA + (buf) * 4096);                        \
    gl16(gB, lB + (buf) * 16384);                       \
    gl16(gB + 8192, lB + (buf) * 16384 + 1024);         \
    gl16(gB + 16384, lB + (buf) * 16384 + 2048);        \
    gl16(gB + 24576, lB + (buf) * 16384 + 3072);        \
    gA += 32; gB += 32;                                 \
  }

  STAGE1(0);
  __syncthreads();
#pragma unroll 2
  for (int k = 0; k < 16; ++k) {
    const int cur = k & 1;
    if (k < 15) STAGE1(cur ^ 1);
    const char* Ab = smem + cur * 4096;
    const char* Bb = smem + 8192 + cur * 16384;
    frag_t a0 = *(const frag_t*)(Ab + afo[0]);
    frag_t a1 = *(const frag_t*)(Ab + afo[1]);
#pragma unroll
    for (int nt = 0; nt < 8; nt++) {
      frag_t bf = *(const frag_t*)(Bb + bfo[nt]);
      acc[0][nt] = MFMA(a0, bf, acc[0][nt]);
      acc[1][nt] = MFMA(a1, bf, acc[1][nt]);
    }
    __syncthreads();
  }
#undef STAGE1

  // ---------------- epi1: bias + LN(256) + gelu -> sH (bf16, XOR swz) ------------
  float bb[8], cg[8], cbv[8];
#pragma unroll
  for (int nt = 0; nt < 8; nt++) {
    int c = h * 256 + wc * 128 + nt * 16 + l15;
    bb[nt] = hb1[c]; cg[nt] = hlng[c]; cbv[nt] = hlnb[c];
  }
  float* sLN = (float*)(smem + 32768);
#pragma unroll
  for (int i = 0; i < 2; i++)
#pragma unroll
    for (int r = 0; r < 4; r++) {
      float s = 0.f, ss = 0.f;
#pragma unroll
      for (int nt = 0; nt < 8; nt++) { float v = acc[i][nt][r] + bb[nt]; s += v; ss = fmaf(v, v, ss); }
#pragma unroll
      for (int m = 1; m < 16; m <<= 1) { s += __shfl_xor(s, m); ss += __shfl_xor(ss, m); }
      if (l15 == 0) {
        int row = wr * 32 + i * 16 + q * 4 + r;
        sLN[row * 4 + wc * 2] = s; sLN[row * 4 + wc * 2 + 1] = ss;
      }
    }
  // attractor ||a||^2 -> sA2 (wave 0 only)
  float* sA2 = (float*)(smem + 37888);
  if (wv == 0) {
    int a = lane >> 3, jj = lane & 7;
    float s = 0.f;
#pragma unroll
    for (int d2 = 0; d2 < 16; d2++) { float v = attr[h * 1024 + a * 128 + jj * 16 + d2]; s = fmaf(v, v, s); }
#pragma unroll
    for (int m = 1; m < 8; m <<= 1) s += __shfl_xor(s, m);
    if (jj == 0) sA2[a] = s;
  }
  // attr as B-frag [a=16(8 valid)][k=d 128] -> sAB @33792 (XOR swz)
#pragma unroll
  for (int j = 0; j < 8; j++) {
    int idx = tid * 8 + j, ar = idx >> 7, d = idx & 127;
    u16 v = (ar < 8) ? f2bf(attr[h * 1024 + ar * 128 + d]) : (u16)0;
    *(u16*)(smem + 33792 + ar * 256 + ((2 * d) ^ ((ar & 7) << 4))) = v;
  }
  __syncthreads();
#pragma unroll
  for (int i = 0; i < 2; i++)
#pragma unroll
    for (int r = 0; r < 4; r++) {
      int row = wr * 32 + i * 16 + q * 4 + r;
      float s = sLN[row * 4] + sLN[row * 4 + 2], ss = sLN[row * 4 + 1] + sLN[row * 4 + 3];
      float mean = s * (1.f / 256.f);
      float rstd = rsqrtf(ss * (1.f / 256.f) - mean * mean + 1e-5f);
      float mr = -mean * rstd;
#pragma unroll
      for (int nt = 0; nt < 8; nt++) {
        float v = fmaf(acc[i][nt][r] + bb[nt], rstd, mr);
        v = fmaf(v, cg[nt], cbv[nt]);
        int col = wc * 128 + nt * 16 + l15;
        *(u16*)(smem + row * 512 + ((2 * col) ^ ((row & 7) << 4))) = f2bf(gelu_f(v));
      }
    }
  __syncthreads();

  // ---------------- phase2: state = H @ W2^T ; B-frags direct from global --------
  f32x4 acc2[8];
#pragma unroll
  for (int nt = 0; nt < 8; nt++) acc2[nt] = vz;
  {
    const int rb2 = (wv * 16 + l15) * 512, sw2 = (l15 & 7) << 4;
    const u16* pB2[8];
#pragma unroll
    for (int nt = 0; nt < 8; nt++)
      pB2[nt] = hW2t + ((((size_t)h * 128) + nt * 16 + l15) << 8) + q * 8;
#pragma unroll
    for (int kb = 0; kb < 256; kb += 32) {
      frag_t af = *(const frag_t*)(smem + rb2 + ((kb * 2 + q * 16) ^ sw2));
#pragma unroll
      for (int nt = 0; nt < 8; nt++) {
        frag_t bf = *(const frag_t*)(pB2[nt] + kb);
        acc2[nt] = MFMA(af, bf, acc2[nt]);
      }
    }
  }
#pragma unroll
  for (int nt = 0; nt < 8; nt++) {
    float b2 = hb2[h * 128 + nt * 16 + l15];
#pragma unroll
    for (int r = 0; r < 4; r++) acc2[nt][r] += b2;
  }
  float s2v[4];
#pragma unroll
  for (int r = 0; r < 4; r++) {
    float s = 0.f;
#pragma unroll
    for (int nt = 0; nt < 8; nt++) s = fmaf(acc2[nt][r], acc2[nt][r], s);
#pragma unroll
    for (int m = 1; m < 16; m <<= 1) s += __shfl_xor(s, m);
    s2v[r] = s;
  }
  __syncthreads();  // sH dead

  // state -> sSt (bf16, XOR swz) ; attrB2[n=col][k=a] -> @20480
#pragma unroll
  for (int nt = 0; nt < 8; nt++)
#pragma unroll
    for (int r = 0; r < 4; r++) {
      int row = wv * 16 + q * 4 + r, col = nt * 16 + l15;
      *(u16*)(smem + row * 256 + ((2 * col) ^ ((row & 7) << 4))) = f2bf(acc2[nt][r]);
    }
#pragma unroll
  for (int j = 0; j < 16; j++) {
    int idx = tid * 16 + j, row = idx >> 5, kk = idx & 31;
    u16 v = (kk < 8) ? f2bf(attr[h * 1024 + kk * 128 + row]) : (u16)0;
    *(u16*)(smem + 20480 + row * 64 + ((2 * kk) ^ ((row & 3) << 4))) = v;
  }
  __syncthreads();

  // ---------------- phase3: dyn = state @ dynT ; sa = state @ attr^T (fused) -----
  f32x4 dacc[8], sacc = vz;
#pragma unroll
  for (int nt = 0; nt < 8; nt++) dacc[nt] = vz;
  {
    const int rb3 = (wv * 16 + l15) * 256, sw3 = (l15 & 7) << 4;
    const u16* pD[8];
#pragma unroll
    for (int nt = 0; nt < 8; nt++)
      pD[nt] = dynT + ((((size_t)h * 128) + nt * 16 + l15) << 7) + q * 8;
#pragma unroll
    for (int kb = 0; kb < 128; kb += 32) {
      const int ko = (kb * 2 + q * 16) ^ sw3;
      frag_t af = *(const frag_t*)(smem + rb3 + ko);
      frag_t ab = *(const frag_t*)(smem + 33792 + l15 * 256 + ko);
      sacc = MFMA(af, ab, sacc);
#pragma unroll
      for (int nt = 0; nt < 8; nt++) {
        frag_t bf = *(const frag_t*)(pD[nt] + kb);
        dacc[nt] = MFMA(af, bf, dacc[nt]);
      }
    }
  }

  // ---------------- softmax over 8 attractors (lane-parallel) --------------------
  const float dscale = 0.088388347648318447f;  // 1/sqrt(128)
  float g01[4];
#pragma unroll
  for (int r = 0; r < 4; r++)
    g01[r] = gate[(t0 + wv * 16 + q * 4 + r) * 4 + h] * 0.1f;
  const float a2l = (l15 < 8) ? ((const float*)(smem + 37888))[l15] : 0.f;
#pragma unroll
  for (int r = 0; r < 4; r++) {
    float lg = -3.0e38f;
    if (l15 < 8) {
      float d2 = fmaxf(fmaf(-2.f, sacc[r], s2v[r] + a2l), 0.f);
      lg = -sqrtf(d2) * dscale;
    }
    float mx = lg;
#pragma unroll
    for (int m = 1; m < 16; m <<= 1) mx = fmaxf(mx, __shfl_xor(mx, m));
    float p = __expf(lg - mx), den = p;
#pragma unroll
    for (int m = 1; m < 16; m <<= 1) den += __shfl_xor(den, m);
    p *= fast_rcp(den);
    int row = wv * 16 + q * 4 + r;
    *(u16*)(smem + 16384 + row * 64 + ((2 * l15) ^ ((row & 3) << 4))) = f2bf(p);
  }

  // pre-combine (frees acc2): pre = state + g*(tanh(dyn) - state)
#pragma unroll
  for (int nt = 0; nt < 8; nt++)
#pragma unroll
    for (int r = 0; r < 4; r++)
      dacc[nt][r] = acc2[nt][r] + g01[r] * (tanh_fast(dacc[nt][r]) - acc2[nt][r]);

  // ---------------- attr_infl = P @ attr  (one K=32 MFMA per col-tile) -----------
  f32x4 aacc[8];
#pragma unroll
  for (int nt = 0; nt < 8; nt++) aacc[nt] = vz;
  {
    const int rowa = wv * 16 + l15;
    frag_t ap = *(const frag_t*)(smem + 16384 + rowa * 64 + ((q * 16) ^ ((l15 & 3) << 4)));
#pragma unroll
    for (int nt = 0; nt < 8; nt++) {
      int rowb = nt * 16 + l15;
      frag_t bf = *(const frag_t*)(smem + 20480 + rowb * 64 + ((q * 16) ^ ((l15 & 3) << 4)));
      aacc[nt] = MFMA(ap, bf, aacc[nt]);
    }
  }

  // ---------------- head_out: wave-local LDS bounce -> 16B coalesced stores ------
#pragma unroll
  for (int r = 0; r < 4; r++) {
    int row = wv * 16 + q * 4 + r;
    int key = (row >> 2) & 3;
#pragma unroll
    for (int nt = 0; nt < 8; nt++) {
      int col = nt * 16 + l15;
      float ho = dacc[nt][r] + g01[r] * aacc[nt][r];
      *(u16*)(smem + row * 256 + ((2 * col) ^ (key << 5))) = f2bf(ho);
    }
  }
  {
    const int row = tid >> 2;              // rows wv*16 .. wv*16+15 for this wave
    const int key = (row >> 2) & 3;
    const long t = t0 + row;
#pragma unroll
    for (int j = 0; j < 4; j++) {
      int c = (tid & 3) + 4 * j;
      uint4 v = *(const uint4*)(smem + row * 256 + ((c << 4) ^ (key << 5)));
      *(uint4*)(outC + t * 1024 + h * 128 + c * 8) = v;
    }
  }
}

// ---------- K3: o1 = gelu(LN(comb @ oW1 + ob1)) ----------
// Round-3 structure (2-phase, per-step __syncthreads) + A-register prefetch one
// K-step ahead (register-only change; sync untouched).
__global__ __launch_bounds__(256, 2) void k3_mlp1(
    const u16* __restrict__ inp, const u16* __restrict__ oW1t,
    const float* __restrict__ ob1, const float* __restrict__ olng, const float* __restrict__ olnb,
    u16* __restrict__ outp) {
  __shared__ __align__(16) char smem[67584];  // 2 x 32KB B slabs + 2KB sLN
  const int tid = threadIdx.x, lane = tid & 63, wv = tid >> 6, q = lane >> 4, l15 = lane & 15;
  const long t0 = (long)blockIdx.x * 64;
  const f32x4 vz = {0.f, 0.f, 0.f, 0.f};
  f32x4 acc[4][8];
#pragma unroll
  for (int i = 0; i < 4; i++)
#pragma unroll
    for (int nt = 0; nt < 8; nt++) acc[i][nt] = vz;

  const int pr = lane >> 3, pos = (lane & 7) ^ pr;
  const int rl = pr * 2 + (pos >> 2), ck = pos & 3;
  const u16* gB = oW1t + ((size_t)(wv * 128 + rl) << 9) + ck * 8;
  int bfo[8];
#pragma unroll
  for (int nt = 0; nt < 8; nt++) {
    int row = wv * 128 + nt * 16 + l15;
    bfo[nt] = (row >> 1) * 128 + (((((row & 1) << 2) | q) ^ ((row >> 1) & 7)) << 4);
  }
  const u16* pA = inp + (((size_t)(t0 + l15)) << 10) + q * 8;

#define STG3(buf, kb)                                                      \
  {                                                                        \
    char* l = smem + (buf) * 32768 + wv * 8192;                            \
    _Pragma("unroll") for (int m = 0; m < 8; m++)                          \
        gl16(gB + m * 8192 + (kb), l + m * 1024);                          \
  }

  frag_t a_c[4], a_n[4];
  STG3(0, 0);
#pragma unroll
  for (int i = 0; i < 4; i++) a_c[i] = *(const frag_t*)(pA + i * 16384);
  __syncthreads();
  for (int k = 0; k < 16; ++k) {
    const int kb = k * 32, cur = k & 1;
    if (k < 15) {
      STG3(cur ^ 1, kb + 32);
#pragma unroll
      for (int i = 0; i < 4; i++) a_n[i] = *(const frag_t*)(pA + i * 16384 + kb + 32);
    }
    const char* Bb = smem + cur * 32768;
#pragma unroll
    for (int nt = 0; nt < 8; nt++) {
      frag_t bf = *(const frag_t*)(Bb + bfo[nt]);
#pragma unroll
      for (int i = 0; i < 4; i++) acc[i][nt] = MFMA(a_c[i], bf, acc[i][nt]);
    }
    __syncthreads();
    if (k < 15) {
#pragma unroll
      for (int i = 0; i < 4; i++) a_c[i] = a_n[i];
    }
  }
#undef STG3

  float bb[8], cg[8], cb2[8];
#pragma unroll
  for (int nt = 0; nt < 8; nt++) {
    int col = wv * 128 + nt * 16 + l15;
    bb[nt] = ob1[col]; cg[nt] = olng[col]; cb2[nt] = olnb[col];
  }
  float* sLN = (float*)(smem + 65536);
#pragma unroll
  for (int i = 0; i < 4; i++)
#pragma unroll
    for (int r = 0; r < 4; r++) {
      float s = 0.f, ss = 0.f;
#pragma unroll
      for (int nt = 0; nt < 8; nt++) { float v = acc[i][nt][r] + bb[nt]; s += v; ss = fmaf(v, v, ss); }
#pragma unroll
      for (int m = 1; m < 16; m <<= 1) { s += __shfl_xor(s, m); ss += __shfl_xor(ss, m); }
      if (l15 == 0) {
        int row = i * 16 + q * 4 + r;
        sLN[row * 8 + wv * 2] = s; sLN[row * 8 + wv * 2 + 1] = ss;
      }
    }
  __syncthreads();
#pragma unroll
  for (int i = 0; i < 4; i++)
#pragma unroll
    for (int r = 0; r < 4; r++) {
      int row = i * 16 + q * 4 + r;
      float4 p0 = *(const float4*)&sLN[row * 8];
      float4 p1 = *(const float4*)&sLN[row * 8 + 4];
      float s = p0.x + p0.z + p1.x + p1.z, ss = p0.y + p0.w + p1.y + p1.w;
      float mean = s * (1.f / 512.f);
      float rstd = rsqrtf(ss * (1.f / 512.f) - mean * mean + 1e-5f);
      const long t = t0 + row;
#pragma unroll
      for (int nt = 0; nt < 8; nt++) {
        int col = wv * 128 + nt * 16 + l15;
        float v = (acc[i][nt][r] + bb[nt] - mean) * rstd * cg[nt] + cb2[nt];
        outp[t * 1024 + col] = f2bf(gelu_f(v));
      }
    }
}

// ---------- K4: out = xn + o1 @ oW2 + ob2 ----------
__global__ __launch_bounds__(256, 2) void k4_mlp2(
    const u16* __restrict__ inp, const u16* __restrict__ oW2t,
    const float* __restrict__ ob2, const u16* __restrict__ xn,
    float* __restrict__ outp) {
  __shared__ __align__(16) char smem[65536];  // 2 x 32KB B slabs
  const int tid = threadIdx.x, lane = tid & 63, wv = tid >> 6, q = lane >> 4, l15 = lane & 15;
  const long t0 = (long)blockIdx.x * 64;
  const f32x4 vz = {0.f, 0.f, 0.f, 0.f};
  f32x4 acc[4][8];
#pragma unroll
  for (int i = 0; i < 4; i++)
#pragma unroll
    for (int nt = 0; nt < 8; nt++) acc[i][nt] = vz;

  const int pr = lane >> 3, pos = (lane & 7) ^ pr;
  const int rl = pr * 2 + (pos >> 2), ck = pos & 3;
  const u16* gB = oW2t + ((size_t)(wv * 128 + rl) << 9) + ck * 8;
  int bfo[8];
#pragma unroll
  for (int nt = 0; nt < 8; nt++) {
    int row = wv * 128 + nt * 16 + l15;
    bfo[nt] = (row >> 1) * 128 + (((((row & 1) << 2) | q) ^ ((row >> 1) & 7)) << 4);
  }
  const u16* pA = inp + (((size_t)(t0 + l15)) << 10) + q * 8;

#define STG4(buf, kb)                                                      \
  {                                                                        \
    char* l = smem + (buf) * 32768 + wv * 8192;                            \
    _Pragma("unroll") for (int m = 0; m < 8; m++)                          \
        gl16(gB + m * 8192 + (kb), l + m * 1024);                          \
  }

  frag_t a_c[4], a_n[4];
  STG4(0, 0);
#pragma unroll
  for (int i = 0; i < 4; i++) a_c[i] = *(const frag_t*)(pA + i * 16384);
  __syncthreads();
  for (int k = 0; k < 16; ++k) {
    const int kb = k * 32, cur = k & 1;
    if (k < 15) {
      STG4(cur ^ 1, kb + 32);
#pragma unroll
      for (int i = 0; i < 4; i++) a_n[i] = *(const frag_t*)(pA + i * 16384 + kb + 32);
    }
    const char* Bb = smem + cur * 32768;
#pragma unroll
    for (int nt = 0; nt < 8; nt++) {
      frag_t bf = *(const frag_t*)(Bb + bfo[nt]);
#pragma unroll
      for (int i = 0; i < 4; i++) acc[i][nt] = MFMA(a_c[i], bf, acc[i][nt]);
    }
    __syncthreads();
    if (k < 15) {
#pragma unroll
      for (int i = 0; i < 4; i++) a_c[i] = a_n[i];
    }
  }
#undef STG4

#pragma unroll
  for (int i = 0; i < 4; i++)
#pragma unroll
    for (int r = 0; r < 4; r++) {
      int row = i * 16 + q * 4 + r;
      const long t = t0 + row;
#pragma unroll
      for (int nt = 0; nt < 8; nt++) {
        int col = wv * 128 + nt * 16 + l15;
        float v = acc[i][nt][r] + ob2[col] + bf2f(xn[t * 512 + col]);
        outp[t * 512 + col] = v;
      }
    }
}

extern "C" void kernel_launch(void* const* d_in, const int* in_sizes, int n_in,
                              void* d_out, int out_size, void* d_ws, size_t ws_size,
                              hipStream_t stream) {
  const float* x    = (const float*)d_in[0];
  const float* ng   = (const float*)d_in[1];
  const float* nbp  = (const float*)d_in[2];
  const float* hW1  = (const float*)d_in[3];
  const float* hb1  = (const float*)d_in[4];
  const float* hlng = (const float*)d_in[5];
  const float* hlnb = (const float*)d_in[6];
  const float* hW2  = (const float*)d_in[7];
  const float* hb2  = (const float*)d_in[8];
  const float* attr = (const float*)d_in[9];
  const float* dyn  = (const float*)d_in[10];
  const float* gW   = (const float*)d_in[11];
  const float* gb   = (const float*)d_in[12];
  const float* oW1  = (const float*)d_in[13];
  const float* ob1  = (const float*)d_in[14];
  const float* olng = (const float*)d_in[15];
  const float* olnb = (const float*)d_in[16];
  const float* oW2  = (const float*)d_in[17];
  const float* ob2  = (const float*)d_in[18];

  char* ws = (char*)d_ws;
  u16*   xn   = (u16*)ws;                   // 67,108,864 B  [65536,512] bf16
  float* gate = (float*)(ws + 67108864);    //  1,048,576 B  [65536,4] f32
  u16*   wT   = (u16*)(ws + 68157440);      //  2,490,368 B  transposed bf16 weights
  u16* hW1t = wT;                // [4][256][512]
  u16* hW2t = wT + 524288;       // [4][128][256]
  u16* dynT = wT + 655360;       // [4][128][128]
  u16* oW1t = wT + 720896;       // [512][512]
  u16* oW2t = wT + 983040;       // [512][512]

  k_tr5<<<4864, 256, 0, stream>>>(hW1, hW2, dyn, oW1, oW2, wT);

  k1_ln_gate<<<16384, 256, 0, stream>>>(x, ng, nbp, gW, gb, xn, gate);

  // d_out doubles as bf16 scratch, per-row interleaved:
  //   row t: u16 [t*1024 .. t*1024+512) = comb, [t*1024+512 .. t*1024+1024) = o1
  u16* cb = (u16*)d_out;
  k2_head<<<4096, 256, 0, stream>>>(xn, hW1t, hb1, hlng, hlnb, hW2t, hb2,
                                    attr, dynT, gate, cb);
  k3_mlp1<<<1024, 256, 0, stream>>>(cb, oW1t, ob1, olng, olnb, cb + 512);
  k4_mlp2<<<1024, 256, 0, stream>>>(cb + 512, oW2t, ob2, xn, (float*)d_out);
}